// Round 1
// baseline (237.444 us; speedup 1.0000x reference)
//
#include <hip/hip_runtime.h>
#include <hip/hip_bf16.h>
#include <math.h>

#define BB 32
#define TT 512
#define SS 128
#define CC 30
#define WW 10
#define DCTX 768
#define DENT 300
#define HH 100
#define EPSF 1e-5f
#define NEGF -1e30f

__device__ __forceinline__ float wave_sum(float v) {
    #pragma unroll
    for (int off = 32; off > 0; off >>= 1) v += __shfl_xor(v, off);
    return v;
}

// ---------------------------------------------------------------------------
// K1: proj = ctx (16384x768) @ proj_W.T (768x300) + proj_b
// f32, 64x64 tile, BK=32, 256 threads, 4x4 microtile.
// ---------------------------------------------------------------------------
__global__ __launch_bounds__(256) void gemm_proj(
    const float* __restrict__ A,     // (B*T, 768)
    const float* __restrict__ Wt,    // (300, 768) row-major (proj_W)
    const float* __restrict__ bias,  // (300)
    float* __restrict__ out)         // (B*T, 300)
{
    __shared__ float As[32][68];   // [k][m], pad to 68 for aligned float4 + bank spread
    __shared__ float Bs[32][68];   // [k][n]
    const int tid = threadIdx.x;
    const int tx = tid & 15, ty = tid >> 4;
    const int row0 = blockIdx.x * 64;
    const int col0 = blockIdx.y * 64;
    float acc[4][4] = {};
    for (int k0 = 0; k0 < DCTX; k0 += 32) {
        #pragma unroll
        for (int i = 0; i < 2; ++i) {
            int f = tid * 2 + i;          // 0..511
            int r = f >> 3;               // 0..63
            int kc = (f & 7) << 2;        // 0,4,..,28
            float4 v = *(const float4*)(A + (size_t)(row0 + r) * DCTX + k0 + kc);
            As[kc+0][r] = v.x; As[kc+1][r] = v.y; As[kc+2][r] = v.z; As[kc+3][r] = v.w;
            int gn = col0 + r;
            float4 w = make_float4(0.f, 0.f, 0.f, 0.f);
            if (gn < DENT) w = *(const float4*)(Wt + (size_t)gn * DCTX + k0 + kc);
            Bs[kc+0][r] = w.x; Bs[kc+1][r] = w.y; Bs[kc+2][r] = w.z; Bs[kc+3][r] = w.w;
        }
        __syncthreads();
        #pragma unroll
        for (int k = 0; k < 32; ++k) {
            float4 av = *(const float4*)&As[k][ty * 4];
            float4 bv = *(const float4*)&Bs[k][tx * 4];
            float a[4] = {av.x, av.y, av.z, av.w};
            float b[4] = {bv.x, bv.y, bv.z, bv.w};
            #pragma unroll
            for (int i = 0; i < 4; ++i)
                #pragma unroll
                for (int j = 0; j < 4; ++j)
                    acc[i][j] = fmaf(a[i], b[j], acc[i][j]);
        }
        __syncthreads();
    }
    #pragma unroll
    for (int i = 0; i < 4; ++i) {
        int r = row0 + ty * 4 + i;
        #pragma unroll
        for (int j = 0; j < 4; ++j) {
            int c = col0 + tx * 4 + j;
            if (c < DENT) out[(size_t)r * DENT + c] = acc[i][j] + bias[c];
        }
    }
}

// ---------------------------------------------------------------------------
// K2: per-(b,s) span extraction: attention logits over W positions, softmax,
// weighted sum of proj rows, span mask, LayerNorm(ln_g, ln_b).
// One wave per (b,s).
// ---------------------------------------------------------------------------
__global__ __launch_bounds__(64) void span_kernel(
    const float* __restrict__ proj,     // (B*T, 300)
    const int*   __restrict__ spans,    // (B*S, 2)
    const float* __restrict__ attn_W,   // (300)
    const float* __restrict__ attn_b,   // (1)
    const float* __restrict__ ln_g,
    const float* __restrict__ ln_b,
    float* __restrict__ span_out)       // (B*S, 300)
{
    const int bs = blockIdx.x;
    const int b = bs / SS;
    const int lane = threadIdx.x;
    const int start = spans[bs * 2 + 0];
    const int end   = spans[bs * 2 + 1];
    const int width = end - start;

    float slog[WW];
    int rowi[WW];
    #pragma unroll
    for (int w = 0; w < WW; ++w) {
        int idx = start + w;
        bool valid = (w <= width) && (idx >= 0) && (idx < TT);
        int ic = valid ? idx : 0;
        rowi[w] = b * TT + ic;
        const float* pr = proj + (size_t)rowi[w] * DENT;
        float p = 0.f;
        #pragma unroll
        for (int dd = 0; dd < 5; ++dd) {
            int d = lane + dd * 64;
            if (d < DENT) p = fmaf(pr[d], attn_W[d], p);
        }
        p = wave_sum(p) + attn_b[0];
        slog[w] = valid ? p : NEGF;
    }
    // softmax over W (identical in every lane)
    float m = slog[0];
    #pragma unroll
    for (int w = 1; w < WW; ++w) m = fmaxf(m, slog[w]);
    float den = 0.f;
    float aw[WW];
    #pragma unroll
    for (int w = 0; w < WW; ++w) { aw[w] = expf(slog[w] - m); den += aw[w]; }
    const float inv = 1.f / den;
    const float msk = (start > -1) ? 1.f : 0.f;

    float acc[5];
    float s1 = 0.f, s2 = 0.f;
    #pragma unroll
    for (int dd = 0; dd < 5; ++dd) {
        int d = lane + dd * 64;
        float v = 0.f;
        if (d < DENT) {
            #pragma unroll
            for (int w = 0; w < WW; ++w)
                v = fmaf(aw[w] * inv, proj[(size_t)rowi[w] * DENT + d], v);
        }
        v *= msk;
        acc[dd] = v;
        s1 += v; s2 += v * v;
    }
    s1 = wave_sum(s1); s2 = wave_sum(s2);
    const float mu = s1 * (1.f / DENT);
    const float var = s2 * (1.f / DENT) - mu * mu;
    const float rstd = rsqrtf(var + EPSF);
    #pragma unroll
    for (int dd = 0; dd < 5; ++dd) {
        int d = lane + dd * 64;
        if (d < DENT)
            span_out[(size_t)bs * DENT + d] = (acc[dd] - mu) * rstd * ln_g[d] + ln_b[d];
    }
}

// ---------------------------------------------------------------------------
// K3: per-(b,s): entity rows -> LDS, KG-LayerNorm stats, score dot, MLP,
// linking softmax over C, weighted entity sum.
// 256 threads (4 waves); wave w handles candidates c = w, w+4, ...
// ---------------------------------------------------------------------------
__global__ __launch_bounds__(256) void final_kernel(
    const float* __restrict__ span_rep,  // (B*S, 300)
    const int*   __restrict__ cand_ent,  // (B*S, 30)
    const float* __restrict__ priors,    // (B*S, 30)
    const float* __restrict__ table,     // (V, 300)
    const float* __restrict__ kg_g,
    const float* __restrict__ kg_b,
    const float* __restrict__ W1,        // (100,2)
    const float* __restrict__ b1,        // (100)
    const float* __restrict__ W2,        // (100)
    const float* __restrict__ b2,        // (1)
    float* __restrict__ out_link,        // (B*S, 30)
    float* __restrict__ out_weighted)    // (B*S, 300)
{
    __shared__ float rows[CC][DENT];
    __shared__ float sr[DENT];
    __shared__ float smu[CC], srs[CC], ssc[CC];
    const int bs = blockIdx.x;
    const int tid = threadIdx.x;
    const int lane = tid & 63;
    const int wv = tid >> 6;

    for (int d = tid; d < DENT; d += 256)
        sr[d] = span_rep[(size_t)bs * DENT + d];
    __syncthreads();

    const float inv_sqrt_d = rsqrtf((float)DENT);
    for (int c = wv; c < CC; c += 4) {
        int e = cand_ent[bs * CC + c];
        const float* tr = table + (size_t)e * DENT;
        float s1 = 0.f, s2 = 0.f;
        float xv[5];
        #pragma unroll
        for (int dd = 0; dd < 5; ++dd) {
            int d = lane + dd * 64;
            float x = 0.f;
            if (d < DENT) { x = tr[d]; rows[c][d] = x; }
            xv[dd] = x;
            s1 += x; s2 += x * x;
        }
        s1 = wave_sum(s1); s2 = wave_sum(s2);
        float mu = s1 * (1.f / DENT);
        float rstd = rsqrtf(s2 * (1.f / DENT) - mu * mu + EPSF);
        // score = dot(span_rep, LN(x)) / sqrt(D)
        float p = 0.f;
        #pragma unroll
        for (int dd = 0; dd < 5; ++dd) {
            int d = lane + dd * 64;
            if (d < DENT) p = fmaf(sr[d], (xv[dd] - mu) * rstd * kg_g[d] + kg_b[d], p);
        }
        p = wave_sum(p) * inv_sqrt_d;
        float prior = priors[bs * CC + c];
        // MLP: h = relu([p, prior] @ W1.T + b1); link = h @ W2.T + b2
        float lp = 0.f;
        for (int j = lane; j < HH; j += 64) {
            float h = W1[j * 2 + 0] * p + W1[j * 2 + 1] * prior + b1[j];
            h = fmaxf(h, 0.f);
            lp = fmaf(W2[j], h, lp);
        }
        lp = wave_sum(lp) + b2[0];
        float link = (e > 0) ? lp : -10000.0f;
        if (lane == 0) { smu[c] = mu; srs[c] = rstd; ssc[c] = link; }
    }
    __syncthreads();

    // softmax over C (redundant in every thread; all reads broadcast from LDS)
    float m = ssc[0];
    #pragma unroll
    for (int c = 1; c < CC; ++c) m = fmaxf(m, ssc[c]);
    float den = 0.f;
    float nrm[CC];
    #pragma unroll
    for (int c = 0; c < CC; ++c) { nrm[c] = expf(ssc[c] - m); den += nrm[c]; }
    const float inv = 1.f / den;

    for (int d = tid; d < DENT; d += 256) {
        float a = 0.f, sn = 0.f;
        #pragma unroll
        for (int c = 0; c < CC; ++c) {
            float n = nrm[c] * inv;
            a = fmaf(n * srs[c], rows[c][d] - smu[c], a);
            sn += n;
        }
        out_weighted[(size_t)bs * DENT + d] = kg_g[d] * a + kg_b[d] * sn;
    }
    for (int c = tid; c < CC; c += 256)
        out_link[bs * CC + c] = ssc[c];
}

extern "C" void kernel_launch(void* const* d_in, const int* in_sizes, int n_in,
                              void* d_out, int out_size, void* d_ws, size_t ws_size,
                              hipStream_t stream) {
    const float* ctx    = (const float*)d_in[0];
    // d_in[1] = mask (unused by reference)
    const int*   spans  = (const int*)d_in[2];
    const int*   cand   = (const int*)d_in[3];
    const float* priors = (const float*)d_in[4];
    // d_in[5] = candidate_segment_ids (unused)
    const float* table  = (const float*)d_in[6];
    const float* projW  = (const float*)d_in[7];
    const float* projb  = (const float*)d_in[8];
    const float* kg_g   = (const float*)d_in[9];
    const float* kg_b   = (const float*)d_in[10];
    const float* ln_g   = (const float*)d_in[11];
    const float* ln_b   = (const float*)d_in[12];
    const float* attW   = (const float*)d_in[13];
    const float* attb   = (const float*)d_in[14];
    const float* W1     = (const float*)d_in[15];
    const float* b1     = (const float*)d_in[16];
    const float* W2     = (const float*)d_in[17];
    const float* b2     = (const float*)d_in[18];

    float* proj     = (float*)d_ws;                       // (B*T, 300)
    float* span_rep = proj + (size_t)BB * TT * DENT;      // (B*S, 300)
    float* out_link = (float*)d_out;                      // (B*S, 30)
    float* out_w    = out_link + (size_t)BB * SS * CC;    // (B*S, 300)

    gemm_proj<<<dim3(BB * TT / 64, (DENT + 63) / 64), 256, 0, stream>>>(
        ctx, projW, projb, proj);
    span_kernel<<<BB * SS, 64, 0, stream>>>(
        proj, spans, attW, attb, ln_g, ln_b, span_rep);
    final_kernel<<<BB * SS, 256, 0, stream>>>(
        span_rep, cand, priors, table, kg_g, kg_b, W1, b1, W2, b2,
        out_link, out_w);
}

// Round 2
// 149.433 us; speedup vs baseline: 1.5890x; 1.5890x over previous
//
#include <hip/hip_runtime.h>
#include <hip/hip_bf16.h>
#include <math.h>

#define BB 32
#define TT 512
#define SS 128
#define CC 30
#define WW 10
#define DCTX 768
#define DENT 300
#define HH 100
#define EPSF 1e-5f
#define NEGF -1e30f

typedef __attribute__((ext_vector_type(8))) short bf16x8;
typedef __attribute__((ext_vector_type(4))) float f32x4;

__device__ __forceinline__ float wave_sum(float v) {
    #pragma unroll
    for (int off = 32; off > 0; off >>= 1) v += __shfl_xor(v, off);
    return v;
}

__device__ __forceinline__ ushort f2bf(float f) {
    __hip_bfloat16 h = __float2bfloat16(f);
    return *reinterpret_cast<ushort*>(&h);
}

// ---------------------------------------------------------------------------
// K1: proj = ctx (16384x768) @ proj_W.T (768x300) + proj_b  -- bf16 MFMA.
// BM=64, BN=320 (covers all N=300 -> A read once), BK=32, 512 threads.
// Conversion f32->bf16 fused into LDS staging.
// ---------------------------------------------------------------------------
#define GBM 64
#define GBN 320
#define GBK 32
#define LDA 40
#define LDB 40

__global__ __launch_bounds__(512) void gemm_proj_mfma(
    const float* __restrict__ A,     // (16384, 768)
    const float* __restrict__ Wt,    // (300, 768)
    const float* __restrict__ bias,  // (300)
    float* __restrict__ out)         // (16384, 300)
{
    __shared__ ushort Al[GBM * LDA];   // 5120 B
    __shared__ ushort Bl[GBN * LDB];   // 25600 B
    const int tid = threadIdx.x;
    const int lane = tid & 63;
    const int wv = tid >> 6;        // 0..7
    const int wm = wv >> 2;         // 0..1 (rows)
    const int wn = wv & 3;          // 0..3 (cols)
    const int m0 = blockIdx.x * GBM;

    const int ar = tid >> 3;        // 0..63
    const int ak = (tid & 7) * 4;   // 0..28

    f32x4 acc[2][5];
    #pragma unroll
    for (int i = 0; i < 2; ++i)
        #pragma unroll
        for (int j = 0; j < 5; ++j)
            acc[i][j] = (f32x4){0.f, 0.f, 0.f, 0.f};

    const int lr = lane & 15;
    const int kq = (lane >> 4) * 8;

    for (int k0 = 0; k0 < DCTX; k0 += GBK) {
        // stage A tile (64x32 f32 -> bf16)
        {
            float4 v = *(const float4*)(A + (size_t)(m0 + ar) * DCTX + k0 + ak);
            ushort4 h;
            h.x = f2bf(v.x); h.y = f2bf(v.y); h.z = f2bf(v.z); h.w = f2bf(v.w);
            *(ushort4*)&Al[ar * LDA + ak] = h;
        }
        // stage B tile (320x32, rows >=300 zero)
        #pragma unroll
        for (int i = 0; i < 5; ++i) {
            int f = tid + i * 512;       // float4 index 0..2559
            int n = f >> 3;
            int kk = (f & 7) * 4;
            float4 v = make_float4(0.f, 0.f, 0.f, 0.f);
            if (n < DENT) v = *(const float4*)(Wt + (size_t)n * DCTX + k0 + kk);
            ushort4 h;
            h.x = f2bf(v.x); h.y = f2bf(v.y); h.z = f2bf(v.z); h.w = f2bf(v.w);
            *(ushort4*)&Bl[n * LDB + kk] = h;
        }
        __syncthreads();
        bf16x8 af[2], bfr[5];
        #pragma unroll
        for (int i = 0; i < 2; ++i)
            af[i] = *(const bf16x8*)&Al[(wm * 32 + i * 16 + lr) * LDA + kq];
        #pragma unroll
        for (int j = 0; j < 5; ++j)
            bfr[j] = *(const bf16x8*)&Bl[(wn * 80 + j * 16 + lr) * LDB + kq];
        #pragma unroll
        for (int i = 0; i < 2; ++i)
            #pragma unroll
            for (int j = 0; j < 5; ++j)
                acc[i][j] = __builtin_amdgcn_mfma_f32_16x16x32_bf16(
                    af[i], bfr[j], acc[i][j], 0, 0, 0);
        __syncthreads();
    }
    const int lq = lane >> 4;
    #pragma unroll
    for (int j = 0; j < 5; ++j) {
        int col = wn * 80 + j * 16 + lr;
        if (col < DENT) {
            float bv = bias[col];
            #pragma unroll
            for (int i = 0; i < 2; ++i)
                #pragma unroll
                for (int r = 0; r < 4; ++r) {
                    int row = m0 + wm * 32 + i * 16 + lq * 4 + r;
                    out[(size_t)row * DENT + col] = acc[i][j][r] + bv;
                }
        }
    }
}

// ---------------------------------------------------------------------------
// K2: per-(b,s) span extraction + LN; emits srg = span_rep*kg_g (for the
// score dot) and scalars SG = sum(srg), SB = sum(span_rep*kg_b).
// One wave per (b,s).
// ---------------------------------------------------------------------------
__global__ __launch_bounds__(64) void span_kernel(
    const float* __restrict__ proj,     // (B*T, 300)
    const int*   __restrict__ spans,    // (B*S, 2)
    const float* __restrict__ attn_W,   // (300)
    const float* __restrict__ attn_b,   // (1)
    const float* __restrict__ ln_g,
    const float* __restrict__ ln_b,
    const float* __restrict__ kg_g,
    const float* __restrict__ kg_b,
    float* __restrict__ srg_out,        // (B*S, 300)
    float* __restrict__ sgsb)           // (B*S, 2)
{
    const int bs = blockIdx.x;
    const int b = bs / SS;
    const int lane = threadIdx.x;
    const int start = spans[bs * 2 + 0];
    const int end   = spans[bs * 2 + 1];
    const int width = end - start;

    float slog[WW];
    int rowi[WW];
    // partial logits first (all loads in flight), then reduce
    #pragma unroll
    for (int w = 0; w < WW; ++w) {
        int idx = start + w;
        bool valid = (w <= width) && (idx >= 0) && (idx < TT);
        rowi[w] = b * TT + (valid ? idx : 0);
        const float* pr = proj + (size_t)rowi[w] * DENT;
        float p = 0.f;
        #pragma unroll
        for (int dd = 0; dd < 5; ++dd) {
            int d = lane + dd * 64;
            if (d < DENT) p = fmaf(pr[d], attn_W[d], p);
        }
        slog[w] = valid ? p : NEGF;
    }
    #pragma unroll
    for (int w = 0; w < WW; ++w) {
        float r = wave_sum(slog[w] == NEGF ? 0.f : slog[w]);
        slog[w] = (slog[w] == NEGF) ? NEGF : r + attn_b[0];
    }
    float m = slog[0];
    #pragma unroll
    for (int w = 1; w < WW; ++w) m = fmaxf(m, slog[w]);
    float den = 0.f;
    float aw[WW];
    #pragma unroll
    for (int w = 0; w < WW; ++w) { aw[w] = expf(slog[w] - m); den += aw[w]; }
    const float inv = 1.f / den;
    const float msk = (start > -1) ? 1.f : 0.f;

    float acc[5];
    float s1 = 0.f, s2 = 0.f;
    #pragma unroll
    for (int dd = 0; dd < 5; ++dd) {
        int d = lane + dd * 64;
        float v = 0.f;
        if (d < DENT) {
            #pragma unroll
            for (int w = 0; w < WW; ++w)
                v = fmaf(aw[w] * inv, proj[(size_t)rowi[w] * DENT + d], v);
        }
        v *= msk;
        acc[dd] = v;
        s1 += v; s2 += v * v;
    }
    #pragma unroll
    for (int off = 32; off > 0; off >>= 1) {
        s1 += __shfl_xor(s1, off);
        s2 += __shfl_xor(s2, off);
    }
    const float mu = s1 * (1.f / DENT);
    const float var = s2 * (1.f / DENT) - mu * mu;
    const float rstd = rsqrtf(var + EPSF);
    float pg = 0.f, pb = 0.f;
    #pragma unroll
    for (int dd = 0; dd < 5; ++dd) {
        int d = lane + dd * 64;
        if (d < DENT) {
            float val = (acc[dd] - mu) * rstd * ln_g[d] + ln_b[d];
            float vg = val * kg_g[d];
            srg_out[(size_t)bs * DENT + d] = vg;
            pg += vg;
            pb += val * kg_b[d];
        }
    }
    #pragma unroll
    for (int off = 32; off > 0; off >>= 1) {
        pg += __shfl_xor(pg, off);
        pb += __shfl_xor(pb, off);
    }
    if (lane == 0) { sgsb[bs * 2 + 0] = pg; sgsb[bs * 2 + 1] = pb; }
}

// ---------------------------------------------------------------------------
// K3a: one WAVE per (b,s,c): gather entity row, fused (sum, sumsq, dot-srg)
// reduction, LN-refactored score, tiny MLP, linking score.
// score = (rstd*(s3 - mu*SG) + SB) / sqrt(D)
// ---------------------------------------------------------------------------
__global__ __launch_bounds__(256) void score_kernel(
    const float* __restrict__ srg,      // (B*S, 300)
    const float* __restrict__ sgsb,     // (B*S, 2)
    const int*   __restrict__ cand,     // (B*S*30)
    const float* __restrict__ priors,   // (B*S*30)
    const float* __restrict__ table,    // (V, 300)
    const float* __restrict__ W1,       // (100,2)
    const float* __restrict__ b1,       // (100)
    const float* __restrict__ W2,       // (100)
    const float* __restrict__ b2,       // (1)
    float*  __restrict__ out_link,      // (B*S*30)
    float4* __restrict__ stats)         // (B*S*30): mu, rstd, link
{
    const int lane = threadIdx.x & 63;
    const int q = blockIdx.x * 4 + (threadIdx.x >> 6);
    const int bs = q / CC;
    const int e = cand[q];

    const float4* row = (const float4*)(table + (size_t)e * DENT);
    const float4* sg4 = (const float4*)(srg + (size_t)bs * DENT);
    const float4 z = make_float4(0.f, 0.f, 0.f, 0.f);
    float4 x0 = row[lane];
    float4 x1 = (lane < 11) ? row[64 + lane] : z;
    float4 g0 = sg4[lane];
    float4 g1 = (lane < 11) ? sg4[64 + lane] : z;

    float s1 = x0.x + x0.y + x0.z + x0.w + x1.x + x1.y + x1.z + x1.w;
    float s2 = x0.x*x0.x + x0.y*x0.y + x0.z*x0.z + x0.w*x0.w
             + x1.x*x1.x + x1.y*x1.y + x1.z*x1.z + x1.w*x1.w;
    float s3 = g0.x*x0.x + g0.y*x0.y + g0.z*x0.z + g0.w*x0.w
             + g1.x*x1.x + g1.y*x1.y + g1.z*x1.z + g1.w*x1.w;
    #pragma unroll
    for (int off = 32; off > 0; off >>= 1) {
        s1 += __shfl_xor(s1, off);
        s2 += __shfl_xor(s2, off);
        s3 += __shfl_xor(s3, off);
    }
    const float mu = s1 * (1.f / DENT);
    const float var = s2 * (1.f / DENT) - mu * mu;
    const float rstd = rsqrtf(var + EPSF);
    const float SG = sgsb[bs * 2 + 0];
    const float SB = sgsb[bs * 2 + 1];
    const float score = (rstd * (s3 - mu * SG) + SB) * rsqrtf((float)DENT);
    const float prior = priors[q];

    int j = lane;  // lane < 64 < 100 always valid
    float h = fmaxf(fmaf(W1[2*j], score, fmaf(W1[2*j+1], prior, b1[j])), 0.f);
    float lp = W2[j] * h;
    if (lane < HH - 64) {
        j = lane + 64;
        float h2 = fmaxf(fmaf(W1[2*j], score, fmaf(W1[2*j+1], prior, b1[j])), 0.f);
        lp = fmaf(W2[j], h2, lp);
    }
    lp = wave_sum(lp) + b2[0];
    const float link = (e > 0) ? lp : -10000.0f;
    if (lane == 0) {
        out_link[q] = link;
        stats[q] = make_float4(mu, rstd, link, 0.f);
    }
}

// ---------------------------------------------------------------------------
// K3b: per-(b,s): softmax over C=30 links, weighted entity sum.
// out[d] = g[d]*(sum_c coef_c*x_cd - sum_c coef_c*mu_c) + b[d]*sum_c n_c
// 320 threads; thread d covers one of 300 dims; 30 gathers in flight.
// ---------------------------------------------------------------------------
__global__ __launch_bounds__(320) void weighted_kernel(
    const int*    __restrict__ cand,
    const float4* __restrict__ stats,
    const float*  __restrict__ table,
    const float*  __restrict__ kg_g,
    const float*  __restrict__ kg_b,
    float* __restrict__ out_w)          // (B*S, 300)
{
    __shared__ float ssc[CC], smu[CC], srs[CC], sexp[CC];
    __shared__ int sid[CC];
    const int bs = blockIdx.x;
    const int tid = threadIdx.x;
    if (tid < CC) {
        float4 st = stats[bs * CC + tid];
        smu[tid] = st.x; srs[tid] = st.y; ssc[tid] = st.z;
        sid[tid] = cand[bs * CC + tid];
    }
    __syncthreads();
    if (tid < CC) {
        float m = ssc[0];
        #pragma unroll
        for (int c = 1; c < CC; ++c) m = fmaxf(m, ssc[c]);
        sexp[tid] = expf(ssc[tid] - m);
    }
    __syncthreads();

    float den = 0.f;
    #pragma unroll
    for (int c = 0; c < CC; ++c) den += sexp[c];
    const float inv = 1.f / den;
    float coef[CC];
    float S2 = 0.f, sn = 0.f;
    #pragma unroll
    for (int c = 0; c < CC; ++c) {
        float n = sexp[c] * inv;
        coef[c] = n * srs[c];
        S2 = fmaf(coef[c], smu[c], S2);
        sn += n;
    }
    const int d = tid;
    if (d < DENT) {
        float xv[CC];
        #pragma unroll
        for (int c = 0; c < CC; ++c)
            xv[c] = table[(size_t)sid[c] * DENT + d];
        float acc = 0.f;
        #pragma unroll
        for (int c = 0; c < CC; ++c) acc = fmaf(coef[c], xv[c], acc);
        out_w[(size_t)bs * DENT + d] = kg_g[d] * (acc - S2) + kg_b[d] * sn;
    }
}

extern "C" void kernel_launch(void* const* d_in, const int* in_sizes, int n_in,
                              void* d_out, int out_size, void* d_ws, size_t ws_size,
                              hipStream_t stream) {
    const float* ctx    = (const float*)d_in[0];
    const int*   spans  = (const int*)d_in[2];
    const int*   cand   = (const int*)d_in[3];
    const float* priors = (const float*)d_in[4];
    const float* table  = (const float*)d_in[6];
    const float* projW  = (const float*)d_in[7];
    const float* projb  = (const float*)d_in[8];
    const float* kg_g   = (const float*)d_in[9];
    const float* kg_b   = (const float*)d_in[10];
    const float* ln_g   = (const float*)d_in[11];
    const float* ln_b   = (const float*)d_in[12];
    const float* attW   = (const float*)d_in[13];
    const float* attb   = (const float*)d_in[14];
    const float* W1     = (const float*)d_in[15];
    const float* b1     = (const float*)d_in[16];
    const float* W2     = (const float*)d_in[17];
    const float* b2     = (const float*)d_in[18];

    // ws layout: [proj 19.66MB | srg 4.92MB | sgsb 32KB]; stats (1.97MB)
    // aliases proj (proj dead after span_kernel, stream-ordered).
    float*  proj  = (float*)d_ws;
    float4* stats = (float4*)d_ws;
    float*  srg   = (float*)((char*)d_ws + (size_t)BB * TT * DENT * 4);
    float*  sgsb  = srg + (size_t)BB * SS * DENT;

    float* out_link = (float*)d_out;                   // (B*S*30)
    float* out_w    = out_link + (size_t)BB * SS * CC; // (B*S*300)

    gemm_proj_mfma<<<dim3(BB * TT / GBM), 512, 0, stream>>>(ctx, projW, projb, proj);
    span_kernel<<<BB * SS, 64, 0, stream>>>(proj, spans, attW, attb,
                                            ln_g, ln_b, kg_g, kg_b, srg, sgsb);
    score_kernel<<<BB * SS * CC / 4, 256, 0, stream>>>(
        srg, sgsb, cand, priors, table, W1, b1, W2, b2, out_link, stats);
    weighted_kernel<<<BB * SS, 320, 0, stream>>>(cand, stats, table, kg_g, kg_b, out_w);
}

// Round 3
// 115.009 us; speedup vs baseline: 2.0646x; 1.2993x over previous
//
#include <hip/hip_runtime.h>
#include <hip/hip_bf16.h>
#include <math.h>

#define BB 32
#define TT 512
#define SS 128
#define CC 30
#define WW 10
#define DCTX 768
#define DENT 300
#define HH 100
#define EPSF 1e-5f
#define NEGF -1e30f

typedef __attribute__((ext_vector_type(8))) short bf16x8;
typedef __attribute__((ext_vector_type(4))) float f32x4;

__device__ __forceinline__ float wave_sum(float v) {
    #pragma unroll
    for (int off = 32; off > 0; off >>= 1) v += __shfl_xor(v, off);
    return v;
}

__device__ __forceinline__ ushort f2bf(float f) {
    __hip_bfloat16 h = __float2bfloat16(f);
    return *reinterpret_cast<ushort*>(&h);
}

__device__ __forceinline__ float dot4(float4 a, float4 b) {
    return a.x*b.x + a.y*b.y + a.z*b.z + a.w*b.w;
}

// ---------------------------------------------------------------------------
// K1: proj = ctx (16384x768) @ proj_W.T (768x300) + proj_b  -- bf16 MFMA.
// BM=64, BN=320 (covers all N=300 -> A read once), BK=32, 512 threads.
// ---------------------------------------------------------------------------
#define GBM 64
#define GBK 32
#define LDA 40
#define LDB 40

__global__ __launch_bounds__(512) void gemm_proj_mfma(
    const float* __restrict__ A,     // (16384, 768)
    const float* __restrict__ Wt,    // (300, 768)
    const float* __restrict__ bias,  // (300)
    float* __restrict__ out)         // (16384, 300)
{
    __shared__ ushort Al[GBM * LDA];
    __shared__ ushort Bl[320 * LDB];
    const int tid = threadIdx.x;
    const int lane = tid & 63;
    const int wv = tid >> 6;
    const int wm = wv >> 2;
    const int wn = wv & 3;
    const int m0 = blockIdx.x * GBM;

    const int ar = tid >> 3;
    const int ak = (tid & 7) * 4;

    f32x4 acc[2][5];
    #pragma unroll
    for (int i = 0; i < 2; ++i)
        #pragma unroll
        for (int j = 0; j < 5; ++j)
            acc[i][j] = (f32x4){0.f, 0.f, 0.f, 0.f};

    const int lr = lane & 15;
    const int kq = (lane >> 4) * 8;

    for (int k0 = 0; k0 < DCTX; k0 += GBK) {
        {
            float4 v = *(const float4*)(A + (size_t)(m0 + ar) * DCTX + k0 + ak);
            ushort4 h;
            h.x = f2bf(v.x); h.y = f2bf(v.y); h.z = f2bf(v.z); h.w = f2bf(v.w);
            *(ushort4*)&Al[ar * LDA + ak] = h;
        }
        #pragma unroll
        for (int i = 0; i < 5; ++i) {
            int f = tid + i * 512;
            int n = f >> 3;
            int kk = (f & 7) * 4;
            float4 v = make_float4(0.f, 0.f, 0.f, 0.f);
            if (n < DENT) v = *(const float4*)(Wt + (size_t)n * DCTX + k0 + kk);
            ushort4 h;
            h.x = f2bf(v.x); h.y = f2bf(v.y); h.z = f2bf(v.z); h.w = f2bf(v.w);
            *(ushort4*)&Bl[n * LDB + kk] = h;
        }
        __syncthreads();
        bf16x8 af[2], bfr[5];
        #pragma unroll
        for (int i = 0; i < 2; ++i)
            af[i] = *(const bf16x8*)&Al[(wm * 32 + i * 16 + lr) * LDA + kq];
        #pragma unroll
        for (int j = 0; j < 5; ++j)
            bfr[j] = *(const bf16x8*)&Bl[(wn * 80 + j * 16 + lr) * LDB + kq];
        #pragma unroll
        for (int i = 0; i < 2; ++i)
            #pragma unroll
            for (int j = 0; j < 5; ++j)
                acc[i][j] = __builtin_amdgcn_mfma_f32_16x16x32_bf16(
                    af[i], bfr[j], acc[i][j], 0, 0, 0);
        __syncthreads();
    }
    const int lq = lane >> 4;
    #pragma unroll
    for (int j = 0; j < 5; ++j) {
        int col = wn * 80 + j * 16 + lr;
        if (col < DENT) {
            float bv = bias[col];
            #pragma unroll
            for (int i = 0; i < 2; ++i)
                #pragma unroll
                for (int r = 0; r < 4; ++r) {
                    int row = m0 + wm * 32 + i * 16 + lq * 4 + r;
                    out[(size_t)row * DENT + col] = acc[i][j][r] + bv;
                }
        }
    }
}

// ---------------------------------------------------------------------------
// K2: per-(b,s) span extraction + LN. float4 loads; the 10 proj rows are
// kept in registers across logits -> softmax -> weighted-sum (single read).
// Emits srg = span_rep*kg_g and SG=sum(srg), SB=sum(span_rep*kg_b).
// ---------------------------------------------------------------------------
__global__ __launch_bounds__(64) void span_kernel(
    const float* __restrict__ proj,     // (B*T, 300)
    const int*   __restrict__ spans,    // (B*S, 2)
    const float* __restrict__ attn_W,   // (300)
    const float* __restrict__ attn_b,   // (1)
    const float* __restrict__ ln_g,
    const float* __restrict__ ln_b,
    const float* __restrict__ kg_g,
    const float* __restrict__ kg_b,
    float* __restrict__ srg_out,        // (B*S, 300)
    float* __restrict__ sgsb)           // (B*S, 2)
{
    const int bs = blockIdx.x;
    const int b = bs >> 7;   // SS = 128
    const int lane = threadIdx.x;
    const int start = spans[bs * 2 + 0];
    const int end   = spans[bs * 2 + 1];
    const int width = end - start;
    const bool lo = lane < 11;   // 75 float4 = 300 floats: lane + (lane+64 if lane<11)
    const float4 z = make_float4(0.f, 0.f, 0.f, 0.f);

    const float4* attW4 = (const float4*)attn_W;
    float4 w0 = attW4[lane];
    float4 w1 = lo ? attW4[64 + lane] : z;

    float4 a0[WW], a1[WW];
    float slog[WW];
    bool vld[WW];
    #pragma unroll
    for (int w = 0; w < WW; ++w) {
        int idx = start + w;
        vld[w] = (w <= width) && (idx >= 0) && (idx < TT);
        const float4* pr = (const float4*)(proj + (size_t)(b * TT + (vld[w] ? idx : 0)) * DENT);
        a0[w] = pr[lane];
        a1[w] = lo ? pr[64 + lane] : z;
        slog[w] = dot4(a0[w], w0) + dot4(a1[w], w1);
    }
    const float ab = attn_b[0];
    #pragma unroll
    for (int w = 0; w < WW; ++w) {
        float r = wave_sum(slog[w]);
        slog[w] = vld[w] ? r + ab : NEGF;
    }
    float m = slog[0];
    #pragma unroll
    for (int w = 1; w < WW; ++w) m = fmaxf(m, slog[w]);
    float den = 0.f;
    float aw[WW];
    #pragma unroll
    for (int w = 0; w < WW; ++w) { aw[w] = expf(slog[w] - m); den += aw[w]; }
    const float inv = 1.f / den;
    const float msk = (start > -1) ? inv : 0.f;

    float4 acc0 = z, acc1 = z;
    #pragma unroll
    for (int w = 0; w < WW; ++w) {
        float c = aw[w] * msk;
        acc0.x = fmaf(c, a0[w].x, acc0.x); acc0.y = fmaf(c, a0[w].y, acc0.y);
        acc0.z = fmaf(c, a0[w].z, acc0.z); acc0.w = fmaf(c, a0[w].w, acc0.w);
        acc1.x = fmaf(c, a1[w].x, acc1.x); acc1.y = fmaf(c, a1[w].y, acc1.y);
        acc1.z = fmaf(c, a1[w].z, acc1.z); acc1.w = fmaf(c, a1[w].w, acc1.w);
    }
    float s1 = acc0.x + acc0.y + acc0.z + acc0.w + acc1.x + acc1.y + acc1.z + acc1.w;
    float s2 = dot4(acc0, acc0) + dot4(acc1, acc1);
    #pragma unroll
    for (int off = 32; off > 0; off >>= 1) {
        s1 += __shfl_xor(s1, off);
        s2 += __shfl_xor(s2, off);
    }
    const float mu = s1 * (1.f / DENT);
    const float rstd = rsqrtf(s2 * (1.f / DENT) - mu * mu + EPSF);

    const float4* lg4 = (const float4*)ln_g;  const float4* lb4 = (const float4*)ln_b;
    const float4* gg4 = (const float4*)kg_g;  const float4* gb4 = (const float4*)kg_b;
    float pg = 0.f, pb = 0.f;
    float4* so = (float4*)(srg_out + (size_t)bs * DENT);
    {
        float4 g = lg4[lane], bb_ = lb4[lane], gg = gg4[lane], gb = gb4[lane];
        float4 val;
        val.x = fmaf((acc0.x - mu) * rstd, g.x, bb_.x);
        val.y = fmaf((acc0.y - mu) * rstd, g.y, bb_.y);
        val.z = fmaf((acc0.z - mu) * rstd, g.z, bb_.z);
        val.w = fmaf((acc0.w - mu) * rstd, g.w, bb_.w);
        float4 vg = make_float4(val.x * gg.x, val.y * gg.y, val.z * gg.z, val.w * gg.w);
        so[lane] = vg;
        pg += vg.x + vg.y + vg.z + vg.w;
        pb += val.x * gb.x + val.y * gb.y + val.z * gb.z + val.w * gb.w;
    }
    if (lo) {
        float4 g = lg4[64 + lane], bb_ = lb4[64 + lane], gg = gg4[64 + lane], gb = gb4[64 + lane];
        float4 val;
        val.x = fmaf((acc1.x - mu) * rstd, g.x, bb_.x);
        val.y = fmaf((acc1.y - mu) * rstd, g.y, bb_.y);
        val.z = fmaf((acc1.z - mu) * rstd, g.z, bb_.z);
        val.w = fmaf((acc1.w - mu) * rstd, g.w, bb_.w);
        float4 vg = make_float4(val.x * gg.x, val.y * gg.y, val.z * gg.z, val.w * gg.w);
        so[64 + lane] = vg;
        pg += vg.x + vg.y + vg.z + vg.w;
        pb += val.x * gb.x + val.y * gb.y + val.z * gb.z + val.w * gb.w;
    }
    #pragma unroll
    for (int off = 32; off > 0; off >>= 1) {
        pg += __shfl_xor(pg, off);
        pb += __shfl_xor(pb, off);
    }
    if (lane == 0) { sgsb[bs * 2 + 0] = pg; sgsb[bs * 2 + 1] = pb; }
}

// ---------------------------------------------------------------------------
// K3: fused scores + softmax + weighted sum. One block per (b,s), 8 waves,
// one wave per candidate (c = wv, wv+8, ...). Entity rows staged in LDS,
// read back for the weighted pass -- table gathered from HBM exactly once.
// score = (rstd*(s3 - mu*SG) + SB) / sqrt(D)
// weighted[d] = g[d]*(sum_c coef_c*x_cd - sum_c coef_c*mu_c) + b[d]*sum_c n_c
// ---------------------------------------------------------------------------
__global__ __launch_bounds__(512) void final_fused(
    const float* __restrict__ srg,      // (B*S, 300)
    const float* __restrict__ sgsb,     // (B*S, 2)
    const int*   __restrict__ cand,     // (B*S*30)
    const float* __restrict__ priors,   // (B*S*30)
    const float* __restrict__ table,    // (V, 300)
    const float* __restrict__ W1,       // (100,2)
    const float* __restrict__ b1,       // (100)
    const float* __restrict__ W2,       // (100)
    const float* __restrict__ b2,       // (1)
    const float* __restrict__ kg_g,
    const float* __restrict__ kg_b,
    float* __restrict__ out_link,       // (B*S*30)
    float* __restrict__ out_w)          // (B*S, 300)
{
    __shared__ float rows[CC][DENT];            // 36000 B
    __shared__ float s_srg[DENT];
    __shared__ float smu[CC], srs[CC], ssc[CC], sexp[CC];
    const int bs = blockIdx.x;
    const int tid = threadIdx.x;
    const int lane = tid & 63;
    const int wv = tid >> 6;
    const bool lo = lane < 11;
    const float4 z = make_float4(0.f, 0.f, 0.f, 0.f);

    if (tid < 75)
        *(float4*)&s_srg[tid * 4] = ((const float4*)(srg + (size_t)bs * DENT))[tid];
    __syncthreads();

    const float SG = sgsb[bs * 2 + 0];
    const float SB = sgsb[bs * 2 + 1];
    const float4 g0 = *(const float4*)&s_srg[lane * 4];
    const float4 g1 = lo ? *(const float4*)&s_srg[256 + lane * 4] : z;

    for (int c = wv; c < CC; c += 8) {
        const int e = cand[bs * CC + c];
        const float4* row = (const float4*)(table + (size_t)e * DENT);
        float4 x0 = row[lane];
        float4 x1 = lo ? row[64 + lane] : z;
        *(float4*)&rows[c][lane * 4] = x0;
        if (lo) *(float4*)&rows[c][256 + lane * 4] = x1;

        float s1 = x0.x + x0.y + x0.z + x0.w + x1.x + x1.y + x1.z + x1.w;
        float s2 = dot4(x0, x0) + dot4(x1, x1);
        float s3 = dot4(g0, x0) + dot4(g1, x1);
        #pragma unroll
        for (int off = 32; off > 0; off >>= 1) {
            s1 += __shfl_xor(s1, off);
            s2 += __shfl_xor(s2, off);
            s3 += __shfl_xor(s3, off);
        }
        const float mu = s1 * (1.f / DENT);
        const float rstd = rsqrtf(s2 * (1.f / DENT) - mu * mu + EPSF);
        const float score = (rstd * (s3 - mu * SG) + SB) * rsqrtf((float)DENT);
        const float prior = priors[bs * CC + c];

        int j = lane;
        float h = fmaxf(fmaf(W1[2*j], score, fmaf(W1[2*j+1], prior, b1[j])), 0.f);
        float lp = W2[j] * h;
        if (lane < HH - 64) {
            j = lane + 64;
            float h2 = fmaxf(fmaf(W1[2*j], score, fmaf(W1[2*j+1], prior, b1[j])), 0.f);
            lp = fmaf(W2[j], h2, lp);
        }
        lp = wave_sum(lp) + b2[0];
        const float link = (e > 0) ? lp : -10000.0f;
        if (lane == 0) {
            smu[c] = mu; srs[c] = rstd; ssc[c] = link;
            out_link[bs * CC + c] = link;
        }
    }
    __syncthreads();

    if (tid < CC) {
        float m = ssc[0];
        #pragma unroll
        for (int c = 1; c < CC; ++c) m = fmaxf(m, ssc[c]);
        sexp[tid] = expf(ssc[tid] - m);
    }
    __syncthreads();

    const int d = tid;
    if (d < DENT) {
        float den = 0.f;
        #pragma unroll
        for (int c = 0; c < CC; ++c) den += sexp[c];
        const float inv = 1.f / den;
        float acc = 0.f, S2 = 0.f, sn = 0.f;
        #pragma unroll
        for (int c = 0; c < CC; ++c) {
            float n = sexp[c] * inv;
            float coef = n * srs[c];
            acc = fmaf(coef, rows[c][d], acc);
            S2 = fmaf(coef, smu[c], S2);
            sn += n;
        }
        out_w[(size_t)bs * DENT + d] = kg_g[d] * (acc - S2) + kg_b[d] * sn;
    }
}

extern "C" void kernel_launch(void* const* d_in, const int* in_sizes, int n_in,
                              void* d_out, int out_size, void* d_ws, size_t ws_size,
                              hipStream_t stream) {
    const float* ctx    = (const float*)d_in[0];
    const int*   spans  = (const int*)d_in[2];
    const int*   cand   = (const int*)d_in[3];
    const float* priors = (const float*)d_in[4];
    const float* table  = (const float*)d_in[6];
    const float* projW  = (const float*)d_in[7];
    const float* projb  = (const float*)d_in[8];
    const float* kg_g   = (const float*)d_in[9];
    const float* kg_b   = (const float*)d_in[10];
    const float* ln_g   = (const float*)d_in[11];
    const float* ln_b   = (const float*)d_in[12];
    const float* attW   = (const float*)d_in[13];
    const float* attb   = (const float*)d_in[14];
    const float* W1     = (const float*)d_in[15];
    const float* b1     = (const float*)d_in[16];
    const float* W2     = (const float*)d_in[17];
    const float* b2     = (const float*)d_in[18];

    float* proj = (float*)d_ws;                           // (B*T, 300)
    float* srg  = proj + (size_t)BB * TT * DENT;          // (B*S, 300)
    float* sgsb = srg + (size_t)BB * SS * DENT;           // (B*S, 2)

    float* out_link = (float*)d_out;                      // (B*S*30)
    float* out_w    = out_link + (size_t)BB * SS * CC;    // (B*S, 300)

    gemm_proj_mfma<<<dim3(BB * TT / GBM), 512, 0, stream>>>(ctx, projW, projb, proj);
    span_kernel<<<BB * SS, 64, 0, stream>>>(proj, spans, attW, attb,
                                            ln_g, ln_b, kg_g, kg_b, srg, sgsb);
    final_fused<<<BB * SS, 512, 0, stream>>>(srg, sgsb, cand, priors, table,
                                             W1, b1, W2, b2, kg_g, kg_b,
                                             out_link, out_w);
}

// Round 4
// 97.311 us; speedup vs baseline: 2.4400x; 1.1819x over previous
//
#include <hip/hip_runtime.h>
#include <hip/hip_bf16.h>
#include <math.h>

#define BB 32
#define TT 512
#define SS 128
#define CC 30
#define WW 10
#define DCTX 768
#define DENT 300
#define HH 100
#define EPSF 1e-5f
#define NEGF -1e30f

typedef __attribute__((ext_vector_type(8))) short bf16x8;
typedef __attribute__((ext_vector_type(4))) float f32x4;

__device__ __forceinline__ float wave_sum(float v) {
    #pragma unroll
    for (int off = 32; off > 0; off >>= 1) v += __shfl_xor(v, off);
    return v;
}

__device__ __forceinline__ ushort f2bf(float f) {
    __hip_bfloat16 h = __float2bfloat16(f);
    return *reinterpret_cast<ushort*>(&h);
}

__device__ __forceinline__ float dot4(float4 a, float4 b) {
    return a.x*b.x + a.y*b.y + a.z*b.z + a.w*b.w;
}
__device__ __forceinline__ float hadd8(float4 a, float4 b) {
    return a.x+a.y+a.z+a.w + b.x+b.y+b.z+b.w;
}
__device__ __forceinline__ ushort4 cvt4(float4 v) {
    ushort4 h; h.x = f2bf(v.x); h.y = f2bf(v.y); h.z = f2bf(v.z); h.w = f2bf(v.w);
    return h;
}

// ---------------------------------------------------------------------------
// K1: proj = ctx (16384x768) @ proj_W.T (768x300) + proj_b  -- bf16 MFMA.
// BM=64, BN=320 (full N -> A read once), BK=32, 512 threads.
// Depth-2 register prefetch + double-buffered LDS, 1 barrier per K-step:
// at step k: load k+2 -> regs, compute LDS[cur] (tile k), cvt+store regs
// (tile k+1) -> LDS[cur^1], barrier.
// ---------------------------------------------------------------------------
#define GBM 64
#define GBK 32
#define LDA 40
#define LDB 40
#define NK  (DCTX / GBK)   // 24

__global__ __launch_bounds__(512) void gemm_proj_mfma(
    const float* __restrict__ A,     // (16384, 768)
    const float* __restrict__ Wt,    // (300, 768)
    const float* __restrict__ bias,  // (300)
    float* __restrict__ out)         // (16384, 300)
{
    __shared__ ushort Al[2][GBM * LDA];
    __shared__ ushort Bl[2][320 * LDB];
    const int tid = threadIdx.x;
    const int lane = tid & 63;
    const int wv = tid >> 6;
    const int wm = wv >> 2;
    const int wn = wv & 3;
    const int m0 = blockIdx.x * GBM;
    const int ar = tid >> 3;
    const int ak = (tid & 7) * 4;
    const float4 z4 = make_float4(0.f, 0.f, 0.f, 0.f);

    int bn[5], bk[5];
    #pragma unroll
    for (int i = 0; i < 5; ++i) { int f = tid + i * 512; bn[i] = f >> 3; bk[i] = (f & 7) * 4; }

    const float* aP = A + (size_t)(m0 + ar) * DCTX + ak;

    f32x4 acc[2][5];
    #pragma unroll
    for (int i = 0; i < 2; ++i)
        #pragma unroll
        for (int j = 0; j < 5; ++j)
            acc[i][j] = (f32x4){0.f, 0.f, 0.f, 0.f};

    const int lr = lane & 15;
    const int kq = (lane >> 4) * 8;

    float4 avA, bvA[5], avB, bvB[5];

#define LOADSET(av_, bv_, K0) do {                                             \
        av_ = *(const float4*)(aP + (K0));                                     \
        _Pragma("unroll")                                                      \
        for (int i_ = 0; i_ < 5; ++i_)                                         \
            bv_[i_] = (bn[i_] < DENT)                                          \
                ? *(const float4*)(Wt + (size_t)bn[i_] * DCTX + (K0) + bk[i_]) \
                : z4;                                                          \
    } while (0)

#define STORESET(BUF, av_, bv_) do {                                           \
        *(ushort4*)&Al[BUF][ar * LDA + ak] = cvt4(av_);                        \
        _Pragma("unroll")                                                      \
        for (int i_ = 0; i_ < 5; ++i_)                                         \
            *(ushort4*)&Bl[BUF][bn[i_] * LDB + bk[i_]] = cvt4(bv_[i_]);        \
    } while (0)

#define COMPUTE(BUF) do {                                                      \
        bf16x8 af_[2], bf_[5];                                                 \
        _Pragma("unroll")                                                      \
        for (int i_ = 0; i_ < 2; ++i_)                                         \
            af_[i_] = *(const bf16x8*)&Al[BUF][(wm*32 + i_*16 + lr)*LDA + kq]; \
        _Pragma("unroll")                                                      \
        for (int j_ = 0; j_ < 5; ++j_)                                         \
            bf_[j_] = *(const bf16x8*)&Bl[BUF][(wn*80 + j_*16 + lr)*LDB + kq]; \
        _Pragma("unroll")                                                      \
        for (int i_ = 0; i_ < 2; ++i_)                                         \
            _Pragma("unroll")                                                  \
            for (int j_ = 0; j_ < 5; ++j_)                                     \
                acc[i_][j_] = __builtin_amdgcn_mfma_f32_16x16x32_bf16(         \
                    af_[i_], bf_[j_], acc[i_][j_], 0, 0, 0);                   \
    } while (0)

    LOADSET(avA, bvA, 0);
    LOADSET(avB, bvB, GBK);
    STORESET(0, avA, bvA);
    __syncthreads();

    #pragma unroll 1
    for (int kk = 0; kk < NK; kk += 2) {
        // even: compute tile kk from LDS0; LDS1 <- set B (tile kk+1); A <- kk+2
        if (kk + 2 < NK) LOADSET(avA, bvA, (kk + 2) * GBK);
        COMPUTE(0);
        STORESET(1, avB, bvB);
        __syncthreads();
        // odd: compute tile kk+1 from LDS1; LDS0 <- set A (tile kk+2); B <- kk+3
        if (kk + 3 < NK) LOADSET(avB, bvB, (kk + 3) * GBK);
        COMPUTE(1);
        if (kk + 2 < NK) STORESET(0, avA, bvA);
        __syncthreads();
    }

    const int lq = lane >> 4;
    #pragma unroll
    for (int j = 0; j < 5; ++j) {
        int col = wn * 80 + j * 16 + lr;
        if (col < DENT) {
            float bv = bias[col];
            #pragma unroll
            for (int i = 0; i < 2; ++i)
                #pragma unroll
                for (int r = 0; r < 4; ++r) {
                    int row = m0 + wm * 32 + i * 16 + lq * 4 + r;
                    out[(size_t)row * DENT + col] = acc[i][j][r] + bv;
                }
        }
    }
}

// ---------------------------------------------------------------------------
// K2: span extraction + LN. 4 spans per block (one wave each), 256 threads.
// 10 proj rows kept in registers across logits -> softmax -> weighted sum.
// Emits srg = span_rep*kg_g and SG=sum(srg), SB=sum(span_rep*kg_b).
// ---------------------------------------------------------------------------
__global__ __launch_bounds__(256) void span_kernel(
    const float* __restrict__ proj,     // (B*T, 300)
    const int*   __restrict__ spans,    // (B*S, 2)
    const float* __restrict__ attn_W,   // (300)
    const float* __restrict__ attn_b,   // (1)
    const float* __restrict__ ln_g,
    const float* __restrict__ ln_b,
    const float* __restrict__ kg_g,
    const float* __restrict__ kg_b,
    float* __restrict__ srg_out,        // (B*S, 300)
    float* __restrict__ sgsb)           // (B*S, 2)
{
    const int bs = blockIdx.x * 4 + (threadIdx.x >> 6);
    const int b = bs >> 7;   // SS = 128
    const int lane = threadIdx.x & 63;
    const int start = spans[bs * 2 + 0];
    const int end   = spans[bs * 2 + 1];
    const int width = end - start;
    const bool lo = lane < 11;
    const float4 z = make_float4(0.f, 0.f, 0.f, 0.f);

    const float4* attW4 = (const float4*)attn_W;
    float4 w0 = attW4[lane];
    float4 w1 = lo ? attW4[64 + lane] : z;

    float4 a0[WW], a1[WW];
    float slog[WW];
    bool vld[WW];
    #pragma unroll
    for (int w = 0; w < WW; ++w) {
        int idx = start + w;
        vld[w] = (w <= width) && (idx >= 0) && (idx < TT);
        const float4* pr = (const float4*)(proj + (size_t)(b * TT + (vld[w] ? idx : 0)) * DENT);
        a0[w] = pr[lane];
        a1[w] = lo ? pr[64 + lane] : z;
        slog[w] = dot4(a0[w], w0) + dot4(a1[w], w1);
    }
    const float ab = attn_b[0];
    #pragma unroll
    for (int w = 0; w < WW; ++w) {
        float r = wave_sum(slog[w]);
        slog[w] = vld[w] ? r + ab : NEGF;
    }
    float m = slog[0];
    #pragma unroll
    for (int w = 1; w < WW; ++w) m = fmaxf(m, slog[w]);
    float den = 0.f;
    float aw[WW];
    #pragma unroll
    for (int w = 0; w < WW; ++w) { aw[w] = expf(slog[w] - m); den += aw[w]; }
    const float inv = 1.f / den;
    const float msk = (start > -1) ? inv : 0.f;

    float4 acc0 = z, acc1 = z;
    #pragma unroll
    for (int w = 0; w < WW; ++w) {
        float c = aw[w] * msk;
        acc0.x = fmaf(c, a0[w].x, acc0.x); acc0.y = fmaf(c, a0[w].y, acc0.y);
        acc0.z = fmaf(c, a0[w].z, acc0.z); acc0.w = fmaf(c, a0[w].w, acc0.w);
        acc1.x = fmaf(c, a1[w].x, acc1.x); acc1.y = fmaf(c, a1[w].y, acc1.y);
        acc1.z = fmaf(c, a1[w].z, acc1.z); acc1.w = fmaf(c, a1[w].w, acc1.w);
    }
    float s1 = hadd8(acc0, acc1);
    float s2 = dot4(acc0, acc0) + dot4(acc1, acc1);
    #pragma unroll
    for (int off = 32; off > 0; off >>= 1) {
        s1 += __shfl_xor(s1, off);
        s2 += __shfl_xor(s2, off);
    }
    const float mu = s1 * (1.f / DENT);
    const float rstd = rsqrtf(s2 * (1.f / DENT) - mu * mu + EPSF);

    const float4* lg4 = (const float4*)ln_g;  const float4* lb4 = (const float4*)ln_b;
    const float4* gg4 = (const float4*)kg_g;  const float4* gb4 = (const float4*)kg_b;
    float pg = 0.f, pb = 0.f;
    float4* so = (float4*)(srg_out + (size_t)bs * DENT);
    {
        float4 g = lg4[lane], bb_ = lb4[lane], gg = gg4[lane], gb = gb4[lane];
        float4 val;
        val.x = fmaf((acc0.x - mu) * rstd, g.x, bb_.x);
        val.y = fmaf((acc0.y - mu) * rstd, g.y, bb_.y);
        val.z = fmaf((acc0.z - mu) * rstd, g.z, bb_.z);
        val.w = fmaf((acc0.w - mu) * rstd, g.w, bb_.w);
        float4 vg = make_float4(val.x * gg.x, val.y * gg.y, val.z * gg.z, val.w * gg.w);
        so[lane] = vg;
        pg += vg.x + vg.y + vg.z + vg.w;
        pb += val.x * gb.x + val.y * gb.y + val.z * gb.z + val.w * gb.w;
    }
    if (lo) {
        float4 g = lg4[64 + lane], bb_ = lb4[64 + lane], gg = gg4[64 + lane], gb = gb4[64 + lane];
        float4 val;
        val.x = fmaf((acc1.x - mu) * rstd, g.x, bb_.x);
        val.y = fmaf((acc1.y - mu) * rstd, g.y, bb_.y);
        val.z = fmaf((acc1.z - mu) * rstd, g.z, bb_.z);
        val.w = fmaf((acc1.w - mu) * rstd, g.w, bb_.w);
        float4 vg = make_float4(val.x * gg.x, val.y * gg.y, val.z * gg.z, val.w * gg.w);
        so[64 + lane] = vg;
        pg += vg.x + vg.y + vg.z + vg.w;
        pb += val.x * gb.x + val.y * gb.y + val.z * gb.z + val.w * gb.w;
    }
    #pragma unroll
    for (int off = 32; off > 0; off >>= 1) {
        pg += __shfl_xor(pg, off);
        pb += __shfl_xor(pb, off);
    }
    if (lane == 0) { sgsb[bs * 2 + 0] = pg; sgsb[bs * 2 + 1] = pb; }
}

// ---------------------------------------------------------------------------
// K3: fused scores + softmax + weighted sum. One block per (b,s), 8 waves.
// Each wave owns candidates {wv, wv+8, wv+16, wv+24} -- ALL row loads issued
// up front (8 float4 in flight), then interleaved reductions, then MLP.
// score = (rstd*(s3 - mu*SG) + SB) / sqrt(D)
// weighted[d] = g[d]*(sum_c coef_c*(x_cd - mu_c)) + b[d]*sum_c n_c
// ---------------------------------------------------------------------------
__global__ __launch_bounds__(512) void final_fused(
    const float* __restrict__ srg,      // (B*S, 300)
    const float* __restrict__ sgsb,     // (B*S, 2)
    const int*   __restrict__ cand,     // (B*S*30)
    const float* __restrict__ priors,   // (B*S*30)
    const float* __restrict__ table,    // (V, 300)
    const float* __restrict__ W1,       // (100,2)
    const float* __restrict__ b1,       // (100)
    const float* __restrict__ W2,       // (100)
    const float* __restrict__ b2,       // (1)
    const float* __restrict__ kg_g,
    const float* __restrict__ kg_b,
    float* __restrict__ out_link,       // (B*S*30)
    float* __restrict__ out_w)          // (B*S, 300)
{
    __shared__ float rows[CC][DENT];            // 36000 B
    __shared__ float smu[CC], srs[CC], ssc[CC], sexp[CC];
    const int bs = blockIdx.x;
    const int tid = threadIdx.x;
    const int lane = tid & 63;
    const int wv = tid >> 6;
    const bool lo = lane < 11;
    const float4 z = make_float4(0.f, 0.f, 0.f, 0.f);

    const int c0 = wv, c1 = wv + 8, c2 = wv + 16, c3 = wv + 24;
    const bool has3 = (c3 < CC);
    const int e0 = cand[bs * CC + c0];
    const int e1 = cand[bs * CC + c1];
    const int e2 = cand[bs * CC + c2];
    const int e3 = has3 ? cand[bs * CC + c3] : e2;

    // issue ALL gathers up front
    const float4* r0 = (const float4*)(table + (size_t)e0 * DENT);
    const float4* r1 = (const float4*)(table + (size_t)e1 * DENT);
    const float4* r2 = (const float4*)(table + (size_t)e2 * DENT);
    const float4* r3 = (const float4*)(table + (size_t)e3 * DENT);
    float4 xa0 = r0[lane], xa1 = r1[lane], xa2 = r2[lane], xa3 = r3[lane];
    float4 xb0 = lo ? r0[64 + lane] : z;
    float4 xb1 = lo ? r1[64 + lane] : z;
    float4 xb2 = lo ? r2[64 + lane] : z;
    float4 xb3 = lo ? r3[64 + lane] : z;

    const float4* sg4 = (const float4*)(srg + (size_t)bs * DENT);
    float4 g0 = sg4[lane];
    float4 g1 = lo ? sg4[64 + lane] : z;
    const float SG = sgsb[bs * 2 + 0];
    const float SB = sgsb[bs * 2 + 1];

    // MLP weights (reused for all 4 candidates)
    const float W1a0 = W1[2 * lane], W1b0 = W1[2 * lane + 1];
    const float B10 = b1[lane], W20 = W2[lane];
    float W1a1 = 0.f, W1b1 = 0.f, B11 = 0.f, W21 = 0.f;
    if (lane < HH - 64) {
        int j = lane + 64;
        W1a1 = W1[2 * j]; W1b1 = W1[2 * j + 1]; B11 = b1[j]; W21 = W2[j];
    }
    const float b2v = b2[0];
    const float p0 = priors[bs * CC + c0];
    const float p1 = priors[bs * CC + c1];
    const float p2 = priors[bs * CC + c2];
    const float p3 = has3 ? priors[bs * CC + c3] : 0.f;

    // park rows in LDS for the weighted pass
    *(float4*)&rows[c0][lane * 4] = xa0;
    *(float4*)&rows[c1][lane * 4] = xa1;
    *(float4*)&rows[c2][lane * 4] = xa2;
    if (has3) *(float4*)&rows[c3][lane * 4] = xa3;
    if (lo) {
        *(float4*)&rows[c0][256 + lane * 4] = xb0;
        *(float4*)&rows[c1][256 + lane * 4] = xb1;
        *(float4*)&rows[c2][256 + lane * 4] = xb2;
        if (has3) *(float4*)&rows[c3][256 + lane * 4] = xb3;
    }

    // 12 interleaved shuffle-reduce chains
    float s1_0 = hadd8(xa0, xb0), s1_1 = hadd8(xa1, xb1);
    float s1_2 = hadd8(xa2, xb2), s1_3 = hadd8(xa3, xb3);
    float s2_0 = dot4(xa0, xa0) + dot4(xb0, xb0), s2_1 = dot4(xa1, xa1) + dot4(xb1, xb1);
    float s2_2 = dot4(xa2, xa2) + dot4(xb2, xb2), s2_3 = dot4(xa3, xa3) + dot4(xb3, xb3);
    float s3_0 = dot4(g0, xa0) + dot4(g1, xb0), s3_1 = dot4(g0, xa1) + dot4(g1, xb1);
    float s3_2 = dot4(g0, xa2) + dot4(g1, xb2), s3_3 = dot4(g0, xa3) + dot4(g1, xb3);
    #pragma unroll
    for (int off = 32; off > 0; off >>= 1) {
        s1_0 += __shfl_xor(s1_0, off); s1_1 += __shfl_xor(s1_1, off);
        s1_2 += __shfl_xor(s1_2, off); s1_3 += __shfl_xor(s1_3, off);
        s2_0 += __shfl_xor(s2_0, off); s2_1 += __shfl_xor(s2_1, off);
        s2_2 += __shfl_xor(s2_2, off); s2_3 += __shfl_xor(s2_3, off);
        s3_0 += __shfl_xor(s3_0, off); s3_1 += __shfl_xor(s3_1, off);
        s3_2 += __shfl_xor(s3_2, off); s3_3 += __shfl_xor(s3_3, off);
    }
    const float isd = rsqrtf((float)DENT);

#define CAND_TAIL(K, CK, EK, PK)                                               \
    do {                                                                       \
        float mu_ = s1_##K * (1.f / DENT);                                     \
        float rstd_ = rsqrtf(s2_##K * (1.f / DENT) - mu_ * mu_ + EPSF);        \
        float score_ = (rstd_ * (s3_##K - mu_ * SG) + SB) * isd;               \
        float h_ = fmaxf(fmaf(W1a0, score_, fmaf(W1b0, PK, B10)), 0.f);        \
        float h2_ = fmaxf(fmaf(W1a1, score_, fmaf(W1b1, PK, B11)), 0.f);       \
        float lp_ = fmaf(W21, h2_, W20 * h_);                                  \
        lp_ = wave_sum(lp_) + b2v;                                             \
        float link_ = (EK > 0) ? lp_ : -10000.0f;                              \
        if (lane == 0) {                                                       \
            smu[CK] = mu_; srs[CK] = rstd_; ssc[CK] = link_;                   \
            out_link[bs * CC + CK] = link_;                                    \
        }                                                                      \
    } while (0)

    CAND_TAIL(0, c0, e0, p0);
    CAND_TAIL(1, c1, e1, p1);
    CAND_TAIL(2, c2, e2, p2);
    if (has3) CAND_TAIL(3, c3, e3, p3);
    __syncthreads();

    if (tid < CC) {
        float m = ssc[0];
        #pragma unroll
        for (int c = 1; c < CC; ++c) m = fmaxf(m, ssc[c]);
        sexp[tid] = expf(ssc[tid] - m);
    }
    __syncthreads();

    const int d = tid;
    if (d < DENT) {
        float den = 0.f;
        #pragma unroll
        for (int c = 0; c < CC; ++c) den += sexp[c];
        const float inv = 1.f / den;
        float acc = 0.f, S2 = 0.f, sn = 0.f;
        #pragma unroll
        for (int c = 0; c < CC; ++c) {
            float n = sexp[c] * inv;
            float coef = n * srs[c];
            acc = fmaf(coef, rows[c][d], acc);
            S2 = fmaf(coef, smu[c], S2);
            sn += n;
        }
        out_w[(size_t)bs * DENT + d] = kg_g[d] * (acc - S2) + kg_b[d] * sn;
    }
}

extern "C" void kernel_launch(void* const* d_in, const int* in_sizes, int n_in,
                              void* d_out, int out_size, void* d_ws, size_t ws_size,
                              hipStream_t stream) {
    const float* ctx    = (const float*)d_in[0];
    const int*   spans  = (const int*)d_in[2];
    const int*   cand   = (const int*)d_in[3];
    const float* priors = (const float*)d_in[4];
    const float* table  = (const float*)d_in[6];
    const float* projW  = (const float*)d_in[7];
    const float* projb  = (const float*)d_in[8];
    const float* kg_g   = (const float*)d_in[9];
    const float* kg_b   = (const float*)d_in[10];
    const float* ln_g   = (const float*)d_in[11];
    const float* ln_b   = (const float*)d_in[12];
    const float* attW   = (const float*)d_in[13];
    const float* attb   = (const float*)d_in[14];
    const float* W1     = (const float*)d_in[15];
    const float* b1     = (const float*)d_in[16];
    const float* W2     = (const float*)d_in[17];
    const float* b2     = (const float*)d_in[18];

    float* proj = (float*)d_ws;                           // (B*T, 300)
    float* srg  = proj + (size_t)BB * TT * DENT;          // (B*S, 300)
    float* sgsb = srg + (size_t)BB * SS * DENT;           // (B*S, 2)

    float* out_link = (float*)d_out;                      // (B*S*30)
    float* out_w    = out_link + (size_t)BB * SS * CC;    // (B*S, 300)

    gemm_proj_mfma<<<dim3(BB * TT / GBM), 512, 0, stream>>>(ctx, projW, projb, proj);
    span_kernel<<<BB * SS / 4, 256, 0, stream>>>(proj, spans, attW, attb,
                                                 ln_g, ln_b, kg_g, kg_b, srg, sgsb);
    final_fused<<<BB * SS, 512, 0, stream>>>(srg, sgsb, cand, priors, table,
                                             W1, b1, W2, b2, kg_g, kg_b,
                                             out_link, out_w);
}